// Round 12
// baseline (287.464 us; speedup 1.0000x reference)
//
#include <hip/hip_runtime.h>
#include <hip/hip_fp16.h>

#define N_NODES 50000
#define HID 128
#define CLS 64

#define NBINS 196        // ceil(50000/256) node bins
#define NBLK 256         // hist/scatter blocks
#define LBUF_CAP 4096    // per-bin CSR staging (bin degree ~3277 + 14 sigma)
#define WTOT 57344       // 3*128*128 + 64*128 weight elements
#define GEMM0_BLOCKS 782 // ceil(3125 tiles / 4 waves)
#define AROW 136         // LDS row stride (128 + 8 pad -> 2-way bank aliasing, free)

typedef __attribute__((ext_vector_type(8))) _Float16 f16x8;
typedef __attribute__((ext_vector_type(4))) float f32x4;

__device__ __forceinline__ float2 u2f2(unsigned int u) {
    union { unsigned int u; __half2 h; } c;
    c.u = u;
    return __half22float2(c.h);
}
__device__ __forceinline__ unsigned int f2u2(float a, float b) {
    union { unsigned int u; __half2 h; } c;
    c.h = __float22half2_rn(make_float2(a, b));
    return c.u;
}

// ---------------- K1: per-(block,bin) histogram + W split ----------------
__global__ __launch_bounds__(256) void hist_wsplit_kernel(
    const int* __restrict__ col, int* __restrict__ hist,
    const float* __restrict__ W0, const float* __restrict__ W1,
    const float* __restrict__ W2, const float* __restrict__ Wl,
    __half* __restrict__ o0h, __half* __restrict__ o0l,
    __half* __restrict__ o1h, __half* __restrict__ o1l,
    __half* __restrict__ o2h, __half* __restrict__ o2l,
    __half* __restrict__ o3h, __half* __restrict__ o3l,
    int E, int chunk) {
    int widx = blockIdx.x * 256 + threadIdx.x;
    if (widx < WTOT) {
        const float* W;
        __half *oh, *ol;
        int NCdim, local;
        if (widx < 16384)      { W = W0; oh = o0h; ol = o0l; NCdim = 128; local = widx; }
        else if (widx < 32768) { W = W1; oh = o1h; ol = o1l; NCdim = 128; local = widx - 16384; }
        else if (widx < 49152) { W = W2; oh = o2h; ol = o2l; NCdim = 128; local = widx - 32768; }
        else                   { W = Wl; oh = o3h; ol = o3l; NCdim = 64;  local = widx - 49152; }
        int nn = local >> 7;
        int k = local & 127;
        float v = W[(size_t)k * NCdim + nn];
        __half h = __float2half_rn(v);
        oh[local] = h;
        ol[local] = __float2half_rn(v - __half2float(h));
    }
    __shared__ int h[NBINS];
    for (int i = threadIdx.x; i < NBINS; i += 256) h[i] = 0;
    __syncthreads();
    int b = blockIdx.x;
    int beg = b * chunk;
    int end = min(E, beg + chunk);
    if (beg < end) {
        int vend = beg + ((end - beg) & ~3);
        for (int i = beg + threadIdx.x * 4; i < vend; i += 1024) {
            int4 c4 = *(const int4*)(col + i);
            atomicAdd(&h[c4.x >> 8], 1);
            atomicAdd(&h[c4.y >> 8], 1);
            atomicAdd(&h[c4.z >> 8], 1);
            atomicAdd(&h[c4.w >> 8], 1);
        }
        int i = vend + threadIdx.x;
        if (i < end) atomicAdd(&h[col[i] >> 8], 1);
    }
    __syncthreads();
    for (int i = threadIdx.x; i < NBINS; i += 256)
        hist[i * NBLK + b] = h[i];  // bin-major, block-minor
}

// ---------------- K2: scatter (self-computed cursors; binBase published) ----------
__global__ __launch_bounds__(256) void scatter_kernel(
    const int* __restrict__ row, const int* __restrict__ col,
    const int* __restrict__ hist, int* __restrict__ binBase_g,
    int* __restrict__ sbuf_src, unsigned char* __restrict__ sbuf_c,
    int E, int chunk) {
    __shared__ int sTot[256];
    __shared__ int cur[NBINS];
    int b = blockIdx.x, t = threadIdx.x;
    int partial = 0, total = 0;
    if (t < NBINS) {
        const int4* r4 = (const int4*)(hist + t * NBLK);
        int nb4 = b >> 2, rem = b & 3;
        for (int j = 0; j < NBLK / 4; ++j) {
            int4 v = r4[j];
            int s = v.x + v.y + v.z + v.w;
            total += s;
            if (j < nb4) partial += s;
            else if (j == nb4) {
                if (rem > 0) partial += v.x;
                if (rem > 1) partial += v.y;
                if (rem > 2) partial += v.z;
            }
        }
    }
    sTot[t] = (t < NBINS) ? total : 0;
    __syncthreads();
#pragma unroll
    for (int off = 1; off < 256; off <<= 1) {
        int u = (t >= off) ? sTot[t - off] : 0;
        __syncthreads();
        sTot[t] += u;
        __syncthreads();
    }
    int myBase = sTot[t] - total;  // exclusive scan value for bin t
    if (t < NBINS) cur[t] = myBase + partial;
    if (b == 0) {
        if (t < NBINS) binBase_g[t] = myBase;
        if (t == 0) binBase_g[NBINS] = E;
    }
    __syncthreads();
    int beg = b * chunk;
    int end = min(E, beg + chunk);
    if (beg >= end) return;
    int vend = beg + ((end - beg) & ~3);
    for (int i = beg + t * 4; i < vend; i += 1024) {
        int4 c4 = *(const int4*)(col + i);
        int4 r4 = *(const int4*)(row + i);
        int p;
        p = atomicAdd(&cur[c4.x >> 8], 1); sbuf_src[p] = r4.x; sbuf_c[p] = (unsigned char)(c4.x & 255);
        p = atomicAdd(&cur[c4.y >> 8], 1); sbuf_src[p] = r4.y; sbuf_c[p] = (unsigned char)(c4.y & 255);
        p = atomicAdd(&cur[c4.z >> 8], 1); sbuf_src[p] = r4.z; sbuf_c[p] = (unsigned char)(c4.z & 255);
        p = atomicAdd(&cur[c4.w >> 8], 1); sbuf_src[p] = r4.w; sbuf_c[p] = (unsigned char)(c4.w & 255);
    }
    int i = vend + t;
    if (i < end) {
        int c = col[i];
        int p = atomicAdd(&cur[c >> 8], 1);
        sbuf_src[p] = row[i];
        sbuf_c[p] = (unsigned char)(c & 255);
    }
}

// ---------------- GEMM body for gemm-0 (A = x fp32, in-register convert) ----------
__device__ __forceinline__ void gemm0_body(
    const float* __restrict__ x, const __half* __restrict__ Bh,
    const __half* __restrict__ Bl, __half* __restrict__ C, int M, int rowTile) {
    constexpr int NT = 8;
    int lane = threadIdx.x & 63;
    int m0 = rowTile << 4;
    if (m0 >= M) return;
    int mr = lane & 15;
    int kq = (lane >> 4) << 3;

    const float*  af = x + (size_t)(m0 + mr) * 128 + kq;
    const __half* bh = Bh + (size_t)mr * 128 + kq;
    const __half* bl = Bl + (size_t)mr * 128 + kq;

    f32x4 acc[NT];
#pragma unroll
    for (int t = 0; t < NT; ++t) acc[t] = (f32x4){0.f, 0.f, 0.f, 0.f};
#pragma unroll
    for (int kc = 0; kc < 128; kc += 32) {
        float4 lo = *(const float4*)(af + kc);
        float4 hi = *(const float4*)(af + kc + 4);
        f16x8 a;
        a[0] = (_Float16)lo.x; a[1] = (_Float16)lo.y;
        a[2] = (_Float16)lo.z; a[3] = (_Float16)lo.w;
        a[4] = (_Float16)hi.x; a[5] = (_Float16)hi.y;
        a[6] = (_Float16)hi.z; a[7] = (_Float16)hi.w;
#pragma unroll
        for (int t = 0; t < NT; ++t) {
            f16x8 wh = *(const f16x8*)(bh + (size_t)t * 16 * 128 + kc);
            f16x8 wl = *(const f16x8*)(bl + (size_t)t * 16 * 128 + kc);
            acc[t] = __builtin_amdgcn_mfma_f32_16x16x32_f16(a, wh, acc[t], 0, 0, 0);
            acc[t] = __builtin_amdgcn_mfma_f32_16x16x32_f16(a, wl, acc[t], 0, 0, 0);
        }
    }
    int r0 = m0 + ((lane >> 4) << 2);
    int cc = lane & 15;
#pragma unroll
    for (int t = 0; t < NT; ++t)
#pragma unroll
        for (int r = 0; r < 4; ++r)
            C[(size_t)(r0 + r) * 128 + t * 16 + cc] =
                __float2half_rn(acc[t][r]);
}

// ---------------- K3: fused csr_place (blocks < NBINS) + GEMM-0 (rest) ------------
__global__ __launch_bounds__(256) void csrplace_gemm0_kernel(
    const int* __restrict__ binBase,
    const int* __restrict__ sbuf_src, const unsigned char* __restrict__ sbuf_c,
    float* __restrict__ dinv, int* __restrict__ row_ptr, int* __restrict__ csr_src,
    const float* __restrict__ x, const __half* __restrict__ W0h,
    const __half* __restrict__ W0l, __half* __restrict__ h2, int n, int E) {
    __shared__ int lcnt[256];
    __shared__ int lcur[256];
    __shared__ int ss[256];
    __shared__ int lbuf[LBUF_CAP];
    int b = blockIdx.x;
    if (b >= NBINS) {
        gemm0_body(x, W0h, W0l, h2, n, (b - NBINS) * 4 + (threadIdx.x >> 6));
        return;
    }
    int t = threadIdx.x;
    lcnt[t] = 0;
    __syncthreads();
    int beg = binBase[b], end = binBase[b + 1];
    for (int j = beg + t; j < end; j += 256)
        atomicAdd(&lcnt[sbuf_c[j]], 1);
    __syncthreads();
    int deg = lcnt[t];
    int node = b * 256 + t;
    if (node < n) dinv[node] = rsqrtf((float)deg + 1.0f);
    ss[t] = deg;
    __syncthreads();
#pragma unroll
    for (int off = 1; off < 256; off <<= 1) {
        int u = (t >= off) ? ss[t - off] : 0;
        __syncthreads();
        ss[t] += u;
        __syncthreads();
    }
    int excl = ss[t] - deg;
    lcur[t] = excl;
    int total = ss[255];
    if (node < n) row_ptr[node] = beg + excl;
    if (b == 0 && t == 0) row_ptr[n] = E;
    __syncthreads();
    for (int j = beg + t; j < end; j += 256) {
        int c = sbuf_c[j];
        int pos = atomicAdd(&lcur[c], 1);
        lbuf[pos] = sbuf_src[j];
    }
    __syncthreads();
    for (int j = t; j < total; j += 256) csr_src[beg + j] = lbuf[j];
}

// ---------------- paired-edge gather: 2 edges per dwordx2, half-wave each ---------
// Each lane accumulates features [foff, foff+4) of its half-wave's edge stream.
__device__ __forceinline__ void gather_batch(
    const __half* __restrict__ h2, int msrc, float mw, int cnt,
    int hw, int foff, float4& acc) {
    int pairs = (cnt + 1) >> 1;
    int j = 0;
    for (; j + 4 <= pairs; j += 4) {
        int i0 = (j << 1) + hw,       i1 = ((j + 1) << 1) + hw;
        int i2 = ((j + 2) << 1) + hw, i3 = ((j + 3) << 1) + hw;
        int s0 = __shfl(msrc, i0), s1 = __shfl(msrc, i1);
        int s2 = __shfl(msrc, i2), s3 = __shfl(msrc, i3);
        float w0 = __shfl(mw, i0), w1 = __shfl(mw, i1);
        float w2 = __shfl(mw, i2), w3 = __shfl(mw, i3);
        uint2 r0 = *(const uint2*)(h2 + ((size_t)s0 << 7) + foff);
        uint2 r1 = *(const uint2*)(h2 + ((size_t)s1 << 7) + foff);
        uint2 r2 = *(const uint2*)(h2 + ((size_t)s2 << 7) + foff);
        uint2 r3 = *(const uint2*)(h2 + ((size_t)s3 << 7) + foff);
        float2 a0 = u2f2(r0.x), b0 = u2f2(r0.y);
        float2 a1 = u2f2(r1.x), b1 = u2f2(r1.y);
        float2 a2 = u2f2(r2.x), b2 = u2f2(r2.y);
        float2 a3 = u2f2(r3.x), b3 = u2f2(r3.y);
        acc.x = fmaf(a0.x, w0, acc.x); acc.y = fmaf(a0.y, w0, acc.y);
        acc.z = fmaf(b0.x, w0, acc.z); acc.w = fmaf(b0.y, w0, acc.w);
        acc.x = fmaf(a1.x, w1, acc.x); acc.y = fmaf(a1.y, w1, acc.y);
        acc.z = fmaf(b1.x, w1, acc.z); acc.w = fmaf(b1.y, w1, acc.w);
        acc.x = fmaf(a2.x, w2, acc.x); acc.y = fmaf(a2.y, w2, acc.y);
        acc.z = fmaf(b2.x, w2, acc.z); acc.w = fmaf(b2.y, w2, acc.w);
        acc.x = fmaf(a3.x, w3, acc.x); acc.y = fmaf(a3.y, w3, acc.y);
        acc.z = fmaf(b3.x, w3, acc.z); acc.w = fmaf(b3.y, w3, acc.w);
    }
    for (; j < pairs; ++j) {
        int i0 = (j << 1) + hw;
        int s0 = __shfl(msrc, i0);
        float w0 = __shfl(mw, i0);
        uint2 r0 = *(const uint2*)(h2 + ((size_t)s0 << 7) + foff);
        float2 a0 = u2f2(r0.x), b0 = u2f2(r0.y);
        acc.x = fmaf(a0.x, w0, acc.x); acc.y = fmaf(a0.y, w0, acc.y);
        acc.z = fmaf(b0.x, w0, acc.z); acc.w = fmaf(b0.y, w0, acc.w);
    }
}

// ---------------- fused agg + GEMM: 16 nodes per block ----------------
// Phase A: 4 waves x 4 nodes aggregate (paired-edge 8B gathers) -> relu -> LDS fp16.
// Phase B: same waves run the 16-row MFMA tile against W (NC cols).
template<int NC, bool HEAD>
__global__ __launch_bounds__(256) void agg_gemm_kernel(
    const __half* __restrict__ h2, const int* __restrict__ row_ptr,
    const int* __restrict__ csr_src, const float* __restrict__ dinv,
    const float* __restrict__ bias,
    const __half* __restrict__ Bh, const __half* __restrict__ Bl,
    const float* __restrict__ gbias, void* __restrict__ Cv, int n) {
    __shared__ __align__(16) __half Als[16][AROW];
    int wave = threadIdx.x >> 6;
    int lane = threadIdx.x & 63;
    int hw = lane >> 5;        // half-wave
    int foff = (lane & 31) << 2;  // 4-half feature slice
    int m0 = blockIdx.x << 4;
    int wid_base = m0 + wave * 4;

    // ---- metadata prefetch for the wave's 4 nodes ----
    int beg4[4], end4[4];
    float dv4[4];
#pragma unroll
    for (int k = 0; k < 4; ++k) {
        beg4[k] = row_ptr[wid_base + k];
        end4[k] = row_ptr[wid_base + k + 1];
        dv4[k] = dinv[wid_base + k];
    }
    int msrc4[4];
#pragma unroll
    for (int k = 0; k < 4; ++k) {
        int cnt = min(64, end4[k] - beg4[k]);
        msrc4[k] = 0;
        if (lane < cnt) msrc4[k] = csr_src[beg4[k] + lane];
    }
    float mw4[4];
#pragma unroll
    for (int k = 0; k < 4; ++k) {
        int cnt = min(64, end4[k] - beg4[k]);
        mw4[k] = 0.f;
        if (lane < cnt) mw4[k] = dinv[msrc4[k]] * dv4[k];
    }

    // ---- Phase A: aggregate ----
#pragma unroll
    for (int k = 0; k < 4; ++k) {
        int wid = wid_base + k;
        float dv = dv4[k];
        float4 acc = make_float4(0.f, 0.f, 0.f, 0.f);
        int cnt0 = min(64, end4[k] - beg4[k]);
        gather_batch(h2, msrc4[k], mw4[k], cnt0, hw, foff, acc);
        for (int base = beg4[k] + 64; base < end4[k]; base += 64) {
            int cnt = min(64, end4[k] - base);
            int msrc = 0;
            float mw = 0.f;
            if (lane < cnt) {
                msrc = csr_src[base + lane];
                mw = dinv[msrc] * dv;
            }
            gather_batch(h2, msrc, mw, cnt, hw, foff, acc);
        }
        // merge half-waves
        acc.x += __shfl_xor(acc.x, 32);
        acc.y += __shfl_xor(acc.y, 32);
        acc.z += __shfl_xor(acc.z, 32);
        acc.w += __shfl_xor(acc.w, 32);
        float sn = dv * dv;
        uint2 sr = *(const uint2*)(h2 + ((size_t)wid << 7) + foff);
        float2 s01 = u2f2(sr.x), s23 = u2f2(sr.y);
        float4 b4 = *(const float4*)(bias + foff);
        float o0 = fmaxf(fmaf(s01.x, sn, acc.x) + b4.x, 0.f);
        float o1 = fmaxf(fmaf(s01.y, sn, acc.y) + b4.y, 0.f);
        float o2 = fmaxf(fmaf(s23.x, sn, acc.z) + b4.z, 0.f);
        float o3 = fmaxf(fmaf(s23.y, sn, acc.w) + b4.w, 0.f);
        if (hw == 0) {
            int lr = wave * 4 + k;
            *(uint2*)&Als[lr][foff] = make_uint2(f2u2(o0, o1), f2u2(o2, o3));
        }
    }
    __syncthreads();

    // ---- Phase B: 16-row GEMM tile, NT column tiles split across 4 waves ----
    constexpr int NT = NC / 16;         // 8 (hidden) or 4 (head)
    constexpr int TPW = NT / 4;         // tiles per wave: 2 or 1
    int mr = lane & 15;
    int kq = (lane >> 4) << 3;
    const __half* bh = Bh + (size_t)mr * 128 + kq;
    const __half* bl = Bl + (size_t)mr * 128 + kq;

    f32x4 acc[TPW];
#pragma unroll
    for (int t = 0; t < TPW; ++t) acc[t] = (f32x4){0.f, 0.f, 0.f, 0.f};
#pragma unroll
    for (int kc = 0; kc < 128; kc += 32) {
        f16x8 a = *(const f16x8*)&Als[mr][kq + kc];
#pragma unroll
        for (int t = 0; t < TPW; ++t) {
            int tile = wave * TPW + t;
            f16x8 wh = *(const f16x8*)(bh + (size_t)tile * 16 * 128 + kc);
            f16x8 wl = *(const f16x8*)(bl + (size_t)tile * 16 * 128 + kc);
            acc[t] = __builtin_amdgcn_mfma_f32_16x16x32_f16(a, wh, acc[t], 0, 0, 0);
            acc[t] = __builtin_amdgcn_mfma_f32_16x16x32_f16(a, wl, acc[t], 0, 0, 0);
        }
    }
    int r0 = m0 + ((lane >> 4) << 2);
    int cc = lane & 15;
#pragma unroll
    for (int t = 0; t < TPW; ++t) {
        int tile = wave * TPW + t;
        float bsv = HEAD ? gbias[tile * 16 + cc] : 0.f;
#pragma unroll
        for (int r = 0; r < 4; ++r) {
            if (r0 + r >= n) break;
            size_t idx = (size_t)(r0 + r) * NC + tile * 16 + cc;
            float val = acc[t][r] + bsv;
            if (HEAD)
                ((float*)Cv)[idx] = val;
            else
                ((__half*)Cv)[idx] = __float2half_rn(val);
        }
    }
}

extern "C" void kernel_launch(void* const* d_in, const int* in_sizes, int n_in,
                              void* d_out, int out_size, void* d_ws, size_t ws_size,
                              hipStream_t stream) {
    const float* x  = (const float*)d_in[0];
    const int* ei   = (const int*)d_in[1];
    const float* W0 = (const float*)d_in[2];
    const float* b0 = (const float*)d_in[3];
    const float* W1 = (const float*)d_in[4];
    const float* b1 = (const float*)d_in[5];
    const float* W2 = (const float*)d_in[6];
    const float* b2 = (const float*)d_in[7];
    const float* Wl = (const float*)d_in[8];
    const float* bl = (const float*)d_in[9];
    float* out = (float*)d_out;

    const int N = N_NODES;
    const int E = in_sizes[1] / 2;
    const int* row = ei;
    const int* col = ei + E;
    const int chunk = (((E + NBLK - 1) / NBLK) + 3) & ~3;  // 4-aligned chunks

    char* ws = (char*)d_ws;
    auto alloc = [&](size_t bytes) {
        char* p = ws;
        ws += (bytes + 255) & ~(size_t)255;
        return p;
    };
    int*   hist    = (int*)alloc((size_t)NBINS * NBLK * 4);
    int*   binBase = (int*)alloc((size_t)(NBINS + 1) * 4);
    int*   sbuf_src= (int*)alloc((size_t)E * 4);
    unsigned char* sbuf_c = (unsigned char*)alloc((size_t)E);
    int*   row_ptr = (int*)alloc((size_t)(N + 1) * 4);
    float* dinv    = (float*)alloc((size_t)N * 4);
    int*   csr_src = (int*)alloc((size_t)E * 4);
    __half* h2a    = (__half*)alloc((size_t)N * HID * 2);
    __half* h2b    = (__half*)alloc((size_t)N * HID * 2);
    __half* Wt_h[4];
    __half* Wt_l[4];
    for (int i = 0; i < 3; ++i) {
        Wt_h[i] = (__half*)alloc((size_t)HID * HID * 2);
        Wt_l[i] = (__half*)alloc((size_t)HID * HID * 2);
    }
    Wt_h[3] = (__half*)alloc((size_t)CLS * HID * 2);
    Wt_l[3] = (__half*)alloc((size_t)CLS * HID * 2);

    // K1: histogram + weight split
    hist_wsplit_kernel<<<NBLK, 256, 0, stream>>>(col, hist, W0, W1, W2, Wl,
        Wt_h[0], Wt_l[0], Wt_h[1], Wt_l[1], Wt_h[2], Wt_l[2], Wt_h[3], Wt_l[3], E, chunk);
    // K2: bin-sorted scatter (self-computed cursors)
    scatter_kernel<<<NBLK, 256, 0, stream>>>(row, col, hist, binBase, sbuf_src, sbuf_c, E, chunk);
    // K3: CSR placement fused with GEMM-0 (independent workloads)
    csrplace_gemm0_kernel<<<NBINS + GEMM0_BLOCKS, 256, 0, stream>>>(
        binBase, sbuf_src, sbuf_c, dinv, row_ptr, csr_src,
        x, Wt_h[0], Wt_l[0], h2a, N, E);

    const int fusedBlocks = (N + 15) / 16;  // 3125

    // K4: agg(layer0) + GEMM@W1
    agg_gemm_kernel<128, false><<<fusedBlocks, 256, 0, stream>>>(
        h2a, row_ptr, csr_src, dinv, b0, Wt_h[1], Wt_l[1], nullptr, h2b, N);
    // K5: agg(layer1) + GEMM@W2
    agg_gemm_kernel<128, false><<<fusedBlocks, 256, 0, stream>>>(
        h2b, row_ptr, csr_src, dinv, b1, Wt_h[2], Wt_l[2], nullptr, h2a, N);
    // K6: agg(layer2) + head GEMM@Wl (+bl, fp32 out)
    agg_gemm_kernel<64, true><<<fusedBlocks, 256, 0, stream>>>(
        h2a, row_ptr, csr_src, dinv, b2, Wt_h[3], Wt_l[3], bl, out, N);
}

// Round 13
// 282.008 us; speedup vs baseline: 1.0193x; 1.0193x over previous
//
#include <hip/hip_runtime.h>
#include <hip/hip_fp16.h>

#define N_NODES 50000
#define HID 128
#define CLS 64

#define NBINS 196        // ceil(50000/256) node bins
#define NBLK 256         // hist/scatter blocks
#define LBUF_CAP 4096    // per-bin CSR staging (bin degree ~3277 + 14 sigma)
#define WTOT 57344       // 3*128*128 + 64*128 weight elements
#define GEMM0_BLOCKS 782 // ceil(3125 tiles / 4 waves)
#define AROW 136         // LDS row stride (128 + 8 pad -> 2-way bank aliasing, free)

typedef __attribute__((ext_vector_type(8))) _Float16 f16x8;
typedef __attribute__((ext_vector_type(4))) float f32x4;

// ---------------- K1: per-(block,bin) histogram + W split ----------------
__global__ __launch_bounds__(256) void hist_wsplit_kernel(
    const int* __restrict__ col, int* __restrict__ hist,
    const float* __restrict__ W0, const float* __restrict__ W1,
    const float* __restrict__ W2, const float* __restrict__ Wl,
    __half* __restrict__ o0h, __half* __restrict__ o0l,
    __half* __restrict__ o1h, __half* __restrict__ o1l,
    __half* __restrict__ o2h, __half* __restrict__ o2l,
    __half* __restrict__ o3h, __half* __restrict__ o3l,
    int E, int chunk) {
    int widx = blockIdx.x * 256 + threadIdx.x;
    if (widx < WTOT) {
        const float* W;
        __half *oh, *ol;
        int NCdim, local;
        if (widx < 16384)      { W = W0; oh = o0h; ol = o0l; NCdim = 128; local = widx; }
        else if (widx < 32768) { W = W1; oh = o1h; ol = o1l; NCdim = 128; local = widx - 16384; }
        else if (widx < 49152) { W = W2; oh = o2h; ol = o2l; NCdim = 128; local = widx - 32768; }
        else                   { W = Wl; oh = o3h; ol = o3l; NCdim = 64;  local = widx - 49152; }
        int nn = local >> 7;
        int k = local & 127;
        float v = W[(size_t)k * NCdim + nn];
        __half h = __float2half_rn(v);
        oh[local] = h;
        ol[local] = __float2half_rn(v - __half2float(h));
    }
    __shared__ int h[NBINS];
    for (int i = threadIdx.x; i < NBINS; i += 256) h[i] = 0;
    __syncthreads();
    int b = blockIdx.x;
    int beg = b * chunk;
    int end = min(E, beg + chunk);
    if (beg < end) {
        int vend = beg + ((end - beg) & ~3);
        for (int i = beg + threadIdx.x * 4; i < vend; i += 1024) {
            int4 c4 = *(const int4*)(col + i);
            atomicAdd(&h[c4.x >> 8], 1);
            atomicAdd(&h[c4.y >> 8], 1);
            atomicAdd(&h[c4.z >> 8], 1);
            atomicAdd(&h[c4.w >> 8], 1);
        }
        int i = vend + threadIdx.x;
        if (i < end) atomicAdd(&h[col[i] >> 8], 1);
    }
    __syncthreads();
    for (int i = threadIdx.x; i < NBINS; i += 256)
        hist[i * NBLK + b] = h[i];  // bin-major, block-minor
}

// ---------------- K2: scatter (self-computed cursors; binBase published) ----------
__global__ __launch_bounds__(256) void scatter_kernel(
    const int* __restrict__ row, const int* __restrict__ col,
    const int* __restrict__ hist, int* __restrict__ binBase_g,
    int* __restrict__ sbuf_src, unsigned char* __restrict__ sbuf_c,
    int E, int chunk) {
    __shared__ int sTot[256];
    __shared__ int cur[NBINS];
    int b = blockIdx.x, t = threadIdx.x;
    int partial = 0, total = 0;
    if (t < NBINS) {
        const int4* r4 = (const int4*)(hist + t * NBLK);
        int nb4 = b >> 2, rem = b & 3;
        for (int j = 0; j < NBLK / 4; ++j) {
            int4 v = r4[j];
            int s = v.x + v.y + v.z + v.w;
            total += s;
            if (j < nb4) partial += s;
            else if (j == nb4) {
                if (rem > 0) partial += v.x;
                if (rem > 1) partial += v.y;
                if (rem > 2) partial += v.z;
            }
        }
    }
    sTot[t] = (t < NBINS) ? total : 0;
    __syncthreads();
#pragma unroll
    for (int off = 1; off < 256; off <<= 1) {
        int u = (t >= off) ? sTot[t - off] : 0;
        __syncthreads();
        sTot[t] += u;
        __syncthreads();
    }
    int myBase = sTot[t] - total;  // exclusive scan value for bin t
    if (t < NBINS) cur[t] = myBase + partial;
    if (b == 0) {
        if (t < NBINS) binBase_g[t] = myBase;
        if (t == 0) binBase_g[NBINS] = E;
    }
    __syncthreads();
    int beg = b * chunk;
    int end = min(E, beg + chunk);
    if (beg >= end) return;
    int vend = beg + ((end - beg) & ~3);
    for (int i = beg + t * 4; i < vend; i += 1024) {
        int4 c4 = *(const int4*)(col + i);
        int4 r4 = *(const int4*)(row + i);
        int p;
        p = atomicAdd(&cur[c4.x >> 8], 1); sbuf_src[p] = r4.x; sbuf_c[p] = (unsigned char)(c4.x & 255);
        p = atomicAdd(&cur[c4.y >> 8], 1); sbuf_src[p] = r4.y; sbuf_c[p] = (unsigned char)(c4.y & 255);
        p = atomicAdd(&cur[c4.z >> 8], 1); sbuf_src[p] = r4.z; sbuf_c[p] = (unsigned char)(c4.z & 255);
        p = atomicAdd(&cur[c4.w >> 8], 1); sbuf_src[p] = r4.w; sbuf_c[p] = (unsigned char)(c4.w & 255);
    }
    int i = vend + t;
    if (i < end) {
        int c = col[i];
        int p = atomicAdd(&cur[c >> 8], 1);
        sbuf_src[p] = row[i];
        sbuf_c[p] = (unsigned char)(c & 255);
    }
}

// ---------------- GEMM body for gemm-0 (A = x fp32, in-register convert) ----------
__device__ __forceinline__ void gemm0_body(
    const float* __restrict__ x, const __half* __restrict__ Bh,
    const __half* __restrict__ Bl, __half* __restrict__ C, int M, int rowTile) {
    constexpr int NT = 8;
    int lane = threadIdx.x & 63;
    int m0 = rowTile << 4;
    if (m0 >= M) return;
    int mr = lane & 15;
    int kq = (lane >> 4) << 3;

    const float*  af = x + (size_t)(m0 + mr) * 128 + kq;
    const __half* bh = Bh + (size_t)mr * 128 + kq;
    const __half* bl = Bl + (size_t)mr * 128 + kq;

    f32x4 acc[NT];
#pragma unroll
    for (int t = 0; t < NT; ++t) acc[t] = (f32x4){0.f, 0.f, 0.f, 0.f};
#pragma unroll
    for (int kc = 0; kc < 128; kc += 32) {
        float4 lo = *(const float4*)(af + kc);
        float4 hi = *(const float4*)(af + kc + 4);
        f16x8 a;
        a[0] = (_Float16)lo.x; a[1] = (_Float16)lo.y;
        a[2] = (_Float16)lo.z; a[3] = (_Float16)lo.w;
        a[4] = (_Float16)hi.x; a[5] = (_Float16)hi.y;
        a[6] = (_Float16)hi.z; a[7] = (_Float16)hi.w;
#pragma unroll
        for (int t = 0; t < NT; ++t) {
            f16x8 wh = *(const f16x8*)(bh + (size_t)t * 16 * 128 + kc);
            f16x8 wl = *(const f16x8*)(bl + (size_t)t * 16 * 128 + kc);
            acc[t] = __builtin_amdgcn_mfma_f32_16x16x32_f16(a, wh, acc[t], 0, 0, 0);
            acc[t] = __builtin_amdgcn_mfma_f32_16x16x32_f16(a, wl, acc[t], 0, 0, 0);
        }
    }
    int r0 = m0 + ((lane >> 4) << 2);
    int cc = lane & 15;
#pragma unroll
    for (int t = 0; t < NT; ++t)
#pragma unroll
        for (int r = 0; r < 4; ++r)
            C[(size_t)(r0 + r) * 128 + t * 16 + cc] =
                __float2half_rn(acc[t][r]);
}

// ---------------- K3: fused csr_place (blocks < NBINS) + GEMM-0 (rest) ------------
__global__ __launch_bounds__(256) void csrplace_gemm0_kernel(
    const int* __restrict__ binBase,
    const int* __restrict__ sbuf_src, const unsigned char* __restrict__ sbuf_c,
    float* __restrict__ dinv, int* __restrict__ row_ptr, int* __restrict__ csr_src,
    const float* __restrict__ x, const __half* __restrict__ W0h,
    const __half* __restrict__ W0l, __half* __restrict__ h2, int n, int E) {
    __shared__ int lcnt[256];
    __shared__ int lcur[256];
    __shared__ int ss[256];
    __shared__ int lbuf[LBUF_CAP];
    int b = blockIdx.x;
    if (b >= NBINS) {
        gemm0_body(x, W0h, W0l, h2, n, (b - NBINS) * 4 + (threadIdx.x >> 6));
        return;
    }
    int t = threadIdx.x;
    lcnt[t] = 0;
    __syncthreads();
    int beg = binBase[b], end = binBase[b + 1];
    for (int j = beg + t; j < end; j += 256)
        atomicAdd(&lcnt[sbuf_c[j]], 1);
    __syncthreads();
    int deg = lcnt[t];
    int node = b * 256 + t;
    if (node < n) dinv[node] = rsqrtf((float)deg + 1.0f);
    ss[t] = deg;
    __syncthreads();
#pragma unroll
    for (int off = 1; off < 256; off <<= 1) {
        int u = (t >= off) ? ss[t - off] : 0;
        __syncthreads();
        ss[t] += u;
        __syncthreads();
    }
    int excl = ss[t] - deg;
    lcur[t] = excl;
    int total = ss[255];
    if (node < n) row_ptr[node] = beg + excl;
    if (b == 0 && t == 0) row_ptr[n] = E;
    __syncthreads();
    for (int j = beg + t; j < end; j += 256) {
        int c = sbuf_c[j];
        int pos = atomicAdd(&lcur[c], 1);
        lbuf[pos] = sbuf_src[j];
    }
    __syncthreads();
    for (int j = t; j < total; j += 256) csr_src[beg + j] = lbuf[j];
}

// ---------------- fused agg + GEMM: 16 nodes per block ----------------
// Phase A: 4 waves x 4 nodes, INTERLEAVED edge loop (4 independent chains,
// full-wave coalesced 4B/lane row gathers; lanes past cnt carry w=0 -> no-op).
// Phase B: same waves run the 16-row MFMA tile against W (NC cols).
template<int NC, bool HEAD>
__global__ __launch_bounds__(256) void agg_gemm_kernel(
    const __half* __restrict__ h2, const int* __restrict__ row_ptr,
    const int* __restrict__ csr_src, const float* __restrict__ dinv,
    const float* __restrict__ bias,
    const __half* __restrict__ Bh, const __half* __restrict__ Bl,
    const float* __restrict__ gbias, void* __restrict__ Cv, int n) {
    __shared__ __align__(16) __half Als[16][AROW];
    int wave = threadIdx.x >> 6;
    int lane = threadIdx.x & 63;
    int loff = lane << 1;
    int m0 = blockIdx.x << 4;
    int wid_base = m0 + wave * 4;   // N = 50000 = 3125*16: always in range

    // ---- metadata prefetch for the wave's 4 nodes ----
    int beg4[4], end4[4], cnt4[4];
    float dv4[4];
#pragma unroll
    for (int k = 0; k < 4; ++k) {
        beg4[k] = row_ptr[wid_base + k];
        end4[k] = row_ptr[wid_base + k + 1];
        dv4[k] = dinv[wid_base + k];
        cnt4[k] = end4[k] - beg4[k];
    }
    int msrc4[4];
#pragma unroll
    for (int k = 0; k < 4; ++k) {
        int c = min(64, cnt4[k]);
        msrc4[k] = 0;
        if (lane < c) msrc4[k] = csr_src[beg4[k] + lane];
    }
    float mw4[4];
#pragma unroll
    for (int k = 0; k < 4; ++k) {
        int c = min(64, cnt4[k]);
        mw4[k] = 0.f;
        if (lane < c) mw4[k] = dinv[msrc4[k]] * dv4[k];
    }

    // ---- Phase A: interleaved aggregation over 4 nodes ----
    float ax[4], ay[4];
#pragma unroll
    for (int k = 0; k < 4; ++k) { ax[k] = 0.f; ay[k] = 0.f; }

    int maxc = max(max(cnt4[0], cnt4[1]), max(cnt4[2], cnt4[3]));
    maxc = min(maxc, 64);
    int j = 0;
    for (; j + 2 <= maxc; j += 2) {
#pragma unroll
        for (int k = 0; k < 4; ++k) {
            int sa = __shfl(msrc4[k], j);
            int sb = __shfl(msrc4[k], j + 1);
            float wa = __shfl(mw4[k], j);
            float wb = __shfl(mw4[k], j + 1);
            float2 va = __half22float2(*(const __half2*)(h2 + ((size_t)sa << 7) + loff));
            float2 vb = __half22float2(*(const __half2*)(h2 + ((size_t)sb << 7) + loff));
            ax[k] = fmaf(va.x, wa, ax[k]); ay[k] = fmaf(va.y, wa, ay[k]);
            ax[k] = fmaf(vb.x, wb, ax[k]); ay[k] = fmaf(vb.y, wb, ay[k]);
        }
    }
    if (j < maxc) {
#pragma unroll
        for (int k = 0; k < 4; ++k) {
            int sa = __shfl(msrc4[k], j);
            float wa = __shfl(mw4[k], j);
            float2 va = __half22float2(*(const __half2*)(h2 + ((size_t)sa << 7) + loff));
            ax[k] = fmaf(va.x, wa, ax[k]); ay[k] = fmaf(va.y, wa, ay[k]);
        }
    }
    // rare fallback: degree > 64
#pragma unroll
    for (int k = 0; k < 4; ++k) {
        for (int base = beg4[k] + 64; base < end4[k]; base += 64) {
            int cnt = min(64, end4[k] - base);
            int msrc = 0;
            float mw = 0.f;
            if (lane < cnt) {
                msrc = csr_src[base + lane];
                mw = dinv[msrc] * dv4[k];
            }
            for (int jj = 0; jj < cnt; ++jj) {
                int s = __shfl(msrc, jj);
                float w = __shfl(mw, jj);
                float2 v = __half22float2(*(const __half2*)(h2 + ((size_t)s << 7) + loff));
                ax[k] = fmaf(v.x, w, ax[k]); ay[k] = fmaf(v.y, w, ay[k]);
            }
        }
    }
    // epilogue: self-loop + bias + relu -> LDS
#pragma unroll
    for (int k = 0; k < 4; ++k) {
        int wid = wid_base + k;
        float sn = dv4[k] * dv4[k];
        float2 self = __half22float2(*(const __half2*)(h2 + ((size_t)wid << 7) + loff));
        float2 b = *(const float2*)(bias + loff);
        float ox = fmaxf(fmaf(self.x, sn, ax[k]) + b.x, 0.f);
        float oy = fmaxf(fmaf(self.y, sn, ay[k]) + b.y, 0.f);
        *(__half2*)&Als[wave * 4 + k][loff] = __float22half2_rn(make_float2(ox, oy));
    }
    __syncthreads();

    // ---- Phase B: 16-row GEMM tile, NT column tiles split across 4 waves ----
    constexpr int NT = NC / 16;         // 8 (hidden) or 4 (head)
    constexpr int TPW = NT / 4;         // tiles per wave: 2 or 1
    int mr = lane & 15;
    int kq = (lane >> 4) << 3;
    const __half* bh = Bh + (size_t)mr * 128 + kq;
    const __half* bl = Bl + (size_t)mr * 128 + kq;

    f32x4 acc[TPW];
#pragma unroll
    for (int t = 0; t < TPW; ++t) acc[t] = (f32x4){0.f, 0.f, 0.f, 0.f};
#pragma unroll
    for (int kc = 0; kc < 128; kc += 32) {
        f16x8 a = *(const f16x8*)&Als[mr][kq + kc];
#pragma unroll
        for (int t = 0; t < TPW; ++t) {
            int tile = wave * TPW + t;
            f16x8 wh = *(const f16x8*)(bh + (size_t)tile * 16 * 128 + kc);
            f16x8 wl = *(const f16x8*)(bl + (size_t)tile * 16 * 128 + kc);
            acc[t] = __builtin_amdgcn_mfma_f32_16x16x32_f16(a, wh, acc[t], 0, 0, 0);
            acc[t] = __builtin_amdgcn_mfma_f32_16x16x32_f16(a, wl, acc[t], 0, 0, 0);
        }
    }
    int r0 = m0 + ((lane >> 4) << 2);
    int cc = lane & 15;
#pragma unroll
    for (int t = 0; t < TPW; ++t) {
        int tile = wave * TPW + t;
        float bsv = HEAD ? gbias[tile * 16 + cc] : 0.f;
#pragma unroll
        for (int r = 0; r < 4; ++r) {
            size_t idx = (size_t)(r0 + r) * NC + tile * 16 + cc;
            float val = acc[t][r] + bsv;
            if (HEAD)
                ((float*)Cv)[idx] = val;
            else
                ((__half*)Cv)[idx] = __float2half_rn(val);
        }
    }
}

extern "C" void kernel_launch(void* const* d_in, const int* in_sizes, int n_in,
                              void* d_out, int out_size, void* d_ws, size_t ws_size,
                              hipStream_t stream) {
    const float* x  = (const float*)d_in[0];
    const int* ei   = (const int*)d_in[1];
    const float* W0 = (const float*)d_in[2];
    const float* b0 = (const float*)d_in[3];
    const float* W1 = (const float*)d_in[4];
    const float* b1 = (const float*)d_in[5];
    const float* W2 = (const float*)d_in[6];
    const float* b2 = (const float*)d_in[7];
    const float* Wl = (const float*)d_in[8];
    const float* bl = (const float*)d_in[9];
    float* out = (float*)d_out;

    const int N = N_NODES;
    const int E = in_sizes[1] / 2;
    const int* row = ei;
    const int* col = ei + E;
    const int chunk = (((E + NBLK - 1) / NBLK) + 3) & ~3;  // 4-aligned chunks

    char* ws = (char*)d_ws;
    auto alloc = [&](size_t bytes) {
        char* p = ws;
        ws += (bytes + 255) & ~(size_t)255;
        return p;
    };
    int*   hist    = (int*)alloc((size_t)NBINS * NBLK * 4);
    int*   binBase = (int*)alloc((size_t)(NBINS + 1) * 4);
    int*   sbuf_src= (int*)alloc((size_t)E * 4);
    unsigned char* sbuf_c = (unsigned char*)alloc((size_t)E);
    int*   row_ptr = (int*)alloc((size_t)(N + 1) * 4);
    float* dinv    = (float*)alloc((size_t)N * 4);
    int*   csr_src = (int*)alloc((size_t)E * 4);
    __half* h2a    = (__half*)alloc((size_t)N * HID * 2);
    __half* h2b    = (__half*)alloc((size_t)N * HID * 2);
    __half* Wt_h[4];
    __half* Wt_l[4];
    for (int i = 0; i < 3; ++i) {
        Wt_h[i] = (__half*)alloc((size_t)HID * HID * 2);
        Wt_l[i] = (__half*)alloc((size_t)HID * HID * 2);
    }
    Wt_h[3] = (__half*)alloc((size_t)CLS * HID * 2);
    Wt_l[3] = (__half*)alloc((size_t)CLS * HID * 2);

    // K1: histogram + weight split
    hist_wsplit_kernel<<<NBLK, 256, 0, stream>>>(col, hist, W0, W1, W2, Wl,
        Wt_h[0], Wt_l[0], Wt_h[1], Wt_l[1], Wt_h[2], Wt_l[2], Wt_h[3], Wt_l[3], E, chunk);
    // K2: bin-sorted scatter (self-computed cursors)
    scatter_kernel<<<NBLK, 256, 0, stream>>>(row, col, hist, binBase, sbuf_src, sbuf_c, E, chunk);
    // K3: CSR placement fused with GEMM-0 (independent workloads)
    csrplace_gemm0_kernel<<<NBINS + GEMM0_BLOCKS, 256, 0, stream>>>(
        binBase, sbuf_src, sbuf_c, dinv, row_ptr, csr_src,
        x, Wt_h[0], Wt_l[0], h2a, N, E);

    const int fusedBlocks = (N + 15) / 16;  // 3125

    // K4: agg(layer0) + GEMM@W1
    agg_gemm_kernel<128, false><<<fusedBlocks, 256, 0, stream>>>(
        h2a, row_ptr, csr_src, dinv, b0, Wt_h[1], Wt_l[1], nullptr, h2b, N);
    // K5: agg(layer1) + GEMM@W2
    agg_gemm_kernel<128, false><<<fusedBlocks, 256, 0, stream>>>(
        h2b, row_ptr, csr_src, dinv, b1, Wt_h[2], Wt_l[2], nullptr, h2a, N);
    // K6: agg(layer2) + head GEMM@Wl (+bl, fp32 out)
    agg_gemm_kernel<64, true><<<fusedBlocks, 256, 0, stream>>>(
        h2a, row_ptr, csr_src, dinv, b2, Wt_h[3], Wt_l[3], bl, out, N);
}